// Round 11
// baseline (1059.818 us; speedup 1.0000x reference)
//
#include <hip/hip_runtime.h>
#include <math.h>

typedef __attribute__((ext_vector_type(8))) short short8;
typedef __attribute__((ext_vector_type(8))) unsigned short ushort8;
typedef __attribute__((ext_vector_type(4))) unsigned short ushort4v;
typedef __attribute__((ext_vector_type(4))) unsigned int uint4v;
typedef __attribute__((ext_vector_type(4))) float f32x4;
typedef __attribute__((ext_vector_type(16))) float f32x16;

__device__ __forceinline__ unsigned short f2bf(float f) {
  union { float f; unsigned u; } v; v.f = f;
  unsigned u = v.u;
  return (unsigned short)((u + 0x7fffu + ((u >> 16) & 1u)) >> 16);
}

__device__ __forceinline__ void gload_lds16(const void* g, void* lds) {
  __builtin_amdgcn_global_load_lds(
      (const __attribute__((address_space(1))) unsigned int*)g,
      (__attribute__((address_space(3))) unsigned int*)lds, 16, 0, 0);
}

// ---------------------------------------------------------------------------
// Transpose+convert body: in f32 [R][C] row-major -> out bf16 [C][R] row-major,
// one 64x64 tile at (r0, c0), using caller-provided LDS (>= 64*65*4 bytes).
// ---------------------------------------------------------------------------
__device__ __forceinline__ void tc_body(const float* __restrict__ in,
                                        unsigned short* __restrict__ outp,
                                        int R, int C, int r0, int c0,
                                        char* smem) {
  float (*tile)[65] = (float(*)[65])smem;
  const int t = threadIdx.x;
  const int tr = t >> 4;
  const int tc = (t & 15) * 4;
#pragma unroll
  for (int p = 0; p < 4; ++p) {
    int r = p * 16 + tr;
    f32x4 v = *(const f32x4*)(in + (size_t)(r0 + r) * C + c0 + tc);
    tile[r][tc] = v[0]; tile[r][tc + 1] = v[1];
    tile[r][tc + 2] = v[2]; tile[r][tc + 3] = v[3];
  }
  __syncthreads();
  const int c = t >> 2;
  const int rb = (t & 3) * 16;
  ushort8 o0, o1;
#pragma unroll
  for (int j = 0; j < 8; ++j) o0[j] = f2bf(tile[rb + j][c]);
#pragma unroll
  for (int j = 0; j < 8; ++j) o1[j] = f2bf(tile[rb + 8 + j][c]);
  unsigned short* dst = outp + (size_t)(c0 + c) * R + r0 + rb;
  *(ushort8*)dst = o0;
  *(ushort8*)(dst + 8) = o1;
}

// ---------------------------------------------------------------------------
// Fused kernel A: blocks [0,4096) = gates; [4096,7680) = small transposes
// (emb_wT 1536, lin_wT0 1024, lin_wT1 1024). All independent.
// ---------------------------------------------------------------------------
__global__ __launch_bounds__(256)
void gates_or_tc(const float* __restrict__ x, const float* __restrict__ w,
                 unsigned short* __restrict__ xg,
                 const float* __restrict__ emb_w, unsigned short* __restrict__ emb_wT,
                 const float* __restrict__ lin_w,
                 unsigned short* __restrict__ lin_wT0,
                 unsigned short* __restrict__ lin_wT1) {
  __shared__ __align__(16) char smem[64 * 65 * 4];
  __shared__ float sred[4][3];
  const int bid = blockIdx.x;
  const int t = threadIdx.x;

  if (bid >= 4096) {
    int b2 = bid - 4096;
    if (b2 < 1536) {
      tc_body(emb_w, emb_wT, 3072, 2048, (b2 >> 5) * 64, (b2 & 31) * 64, smem);
    } else {
      int b3 = b2 - 1536;
      const float* in = (b3 < 1024) ? lin_w : (lin_w + 2048 * 2048);
      unsigned short* outp = (b3 < 1024) ? lin_wT0 : lin_wT1;
      b3 &= 1023;
      tc_body(in, outp, 2048, 2048, (b3 >> 5) * 64, (b3 & 31) * 64, smem);
    }
    return;
  }

  const int n = bid;
  const float* xr = x + (size_t)n * 3072;
  f32x4 xv[3];
#pragma unroll
  for (int c = 0; c < 3; ++c)
    xv[c] = *(const f32x4*)(xr + c * 1024 + t * 4);

  float p[3] = {0.f, 0.f, 0.f};
#pragma unroll
  for (int l = 0; l < 3; ++l) {
#pragma unroll
    for (int c = 0; c < 3; ++c) {
      f32x4 wv = *(const f32x4*)(w + l * 3072 + c * 1024 + t * 4);
      p[l] += xv[c][0] * wv[0] + xv[c][1] * wv[1] + xv[c][2] * wv[2] + xv[c][3] * wv[3];
    }
  }
#pragma unroll
  for (int off = 32; off; off >>= 1) {
    p[0] += __shfl_xor(p[0], off);
    p[1] += __shfl_xor(p[1], off);
    p[2] += __shfl_xor(p[2], off);
  }
  const int wave = t >> 6, lane = t & 63;
  if (lane == 0) {
    sred[wave][0] = p[0]; sred[wave][1] = p[1]; sred[wave][2] = p[2];
  }
  __syncthreads();
  float g[3];
#pragma unroll
  for (int l = 0; l < 3; ++l) {
    float s = sred[0][l] + sred[1][l] + sred[2][l] + sred[3][l];
    g[l] = 1.f / (1.f + expf(-s));
  }
  unsigned short* orow = xg + (size_t)n * 3072;
#pragma unroll
  for (int c = 0; c < 3; ++c) {
    ushort4v o;
#pragma unroll
    for (int j = 0; j < 4; ++j) o[j] = f2bf(xv[c][j] * g[c]);
    *(ushort4v*)(orow + c * 1024 + t * 4) = o;
  }
}

// ---------------------------------------------------------------------------
// Fused kernel B: blocks [0,512) = mid GEMM 0 (h0 = relu(xg @ emb_wT^T + b)),
// blocks [512, 512+16000) = out_w transpose (2048 x 32000 -> 32000 x 2048).
// ---------------------------------------------------------------------------
__global__ __launch_bounds__(256)
void gemm0_or_tc(const unsigned short* __restrict__ A,
                 const unsigned short* __restrict__ Bt,
                 const float* __restrict__ bias,
                 unsigned short* __restrict__ Cb,
                 const float* __restrict__ tc_in,
                 unsigned short* __restrict__ tc_out,
                 int do_tc) {
  __shared__ __align__(16) char smem[32768];
  const int bid = blockIdx.x;

  if (bid >= 512) {
    int b2 = bid - 512;
    tc_body(tc_in, tc_out, 2048, 32000, (b2 / 500) * 64, (b2 % 500) * 64, smem);
    return;
  }
  (void)do_tc;

  unsigned short* As = (unsigned short*)smem;
  unsigned short* Bs = (unsigned short*)(smem + 16384);
  constexpr int K = 3072, N = 2048;

  const int tid = threadIdx.x;
  const int lane = tid & 63;
  const int wv = tid >> 6;
  const int wm = wv >> 1, wn = wv & 1;
  const int lid = (bid & 7) * 64 + (bid >> 3);   // XCD swizzle over 512 blocks
  const int mt = lid & 31;
  const int nt = lid >> 5;
  const int m0 = mt * 128, n0 = nt * 128;
  const size_t strideB = (size_t)K * 2;

  f32x4 acc[4][4] = {};

  for (int kt = 0; kt < K; kt += 64) {
    __syncthreads();
#pragma unroll
    for (int i = 0; i < 4; ++i) {
      const int o = wv * 4096 + i * 1024 + lane * 16;
      const int row = o >> 7;
      const int sw = (((o >> 4) & 7) * 16) ^ ((row & 7) << 4);
      gload_lds16((const char*)A + (size_t)(m0 + row) * strideB + (size_t)kt * 2 + sw,
                  (char*)As + wv * 4096 + i * 1024);
      gload_lds16((const char*)Bt + (size_t)(n0 + row) * strideB + (size_t)kt * 2 + sw,
                  (char*)Bs + wv * 4096 + i * 1024);
    }
    __syncthreads();
#pragma unroll
    for (int kk = 0; kk < 2; ++kk) {
      short8 av[4], bv[4];
      const int kb = kk * 64 + (lane >> 4) * 16;
#pragma unroll
      for (int mi = 0; mi < 4; ++mi) {
        int row = wm * 64 + mi * 16 + (lane & 15);
        av[mi] = *(const short8*)((const char*)As + row * 128 + (kb ^ ((row & 7) << 4)));
      }
#pragma unroll
      for (int ni = 0; ni < 4; ++ni) {
        int row = wn * 64 + ni * 16 + (lane & 15);
        bv[ni] = *(const short8*)((const char*)Bs + row * 128 + (kb ^ ((row & 7) << 4)));
      }
#pragma unroll
      for (int mi = 0; mi < 4; ++mi)
#pragma unroll
        for (int ni = 0; ni < 4; ++ni)
          acc[mi][ni] = __builtin_amdgcn_mfma_f32_16x16x32_bf16(av[mi], bv[ni], acc[mi][ni], 0, 0, 0);
    }
  }

  const int lr = lane >> 4, lc = lane & 15;
#pragma unroll
  for (int ni = 0; ni < 4; ++ni) {
    int c = n0 + wn * 64 + ni * 16 + lc;
    float bb = bias[c] + bias[N + c] + bias[2 * N + c];
#pragma unroll
    for (int mi = 0; mi < 4; ++mi) {
      int r0 = m0 + wm * 64 + mi * 16 + lr * 4;
      f32x4 v = acc[mi][ni];
#pragma unroll
      for (int j = 0; j < 4; ++j) {
        float val = v[j] + bb;
        val = val > 0.f ? val : 0.f;
        Cb[(size_t)(r0 + j) * N + c] = f2bf(val);
      }
    }
  }
}

// ---------------------------------------------------------------------------
// Mid GEMM (proven, m97-structure): C[4096, N] = A(bf16) @ Bt(bf16)^T
// + XCD-aware block swizzle (grid % 8 == 0).
// ---------------------------------------------------------------------------
template <int EPI>
__global__ __launch_bounds__(256)
void gemm_tt(const unsigned short* __restrict__ A,
             const unsigned short* __restrict__ Bt,
             const float* __restrict__ bias,
             unsigned short* __restrict__ Cb,
             float* __restrict__ Cf,
             int K, int N) {
  __shared__ __align__(16) unsigned short As[128 * 64];
  __shared__ __align__(16) unsigned short Bs[128 * 64];

  const int tid = threadIdx.x;
  const int lane = tid & 63;
  const int wv = tid >> 6;
  const int wm = wv >> 1, wn = wv & 1;
  const int bid = blockIdx.x;
  const int cpx = gridDim.x >> 3;
  const int lid = (bid & 7) * cpx + (bid >> 3);   // XCD swizzle (grid%8==0)
  const int mt = lid & 31;
  const int nt = lid >> 5;
  const int m0 = mt * 128, n0 = nt * 128;
  const size_t strideB = (size_t)K * 2;

  f32x4 acc[4][4] = {};

  for (int kt = 0; kt < K; kt += 64) {
    __syncthreads();
#pragma unroll
    for (int i = 0; i < 4; ++i) {
      const int o = wv * 4096 + i * 1024 + lane * 16;
      const int row = o >> 7;
      const int sw = (((o >> 4) & 7) * 16) ^ ((row & 7) << 4);
      gload_lds16((const char*)A + (size_t)(m0 + row) * strideB + (size_t)kt * 2 + sw,
                  (char*)As + wv * 4096 + i * 1024);
      gload_lds16((const char*)Bt + (size_t)(n0 + row) * strideB + (size_t)kt * 2 + sw,
                  (char*)Bs + wv * 4096 + i * 1024);
    }
    __syncthreads();
#pragma unroll
    for (int kk = 0; kk < 2; ++kk) {
      short8 av[4], bv[4];
      const int kb = kk * 64 + (lane >> 4) * 16;
#pragma unroll
      for (int mi = 0; mi < 4; ++mi) {
        int row = wm * 64 + mi * 16 + (lane & 15);
        av[mi] = *(const short8*)((const char*)As + row * 128 + (kb ^ ((row & 7) << 4)));
      }
#pragma unroll
      for (int ni = 0; ni < 4; ++ni) {
        int row = wn * 64 + ni * 16 + (lane & 15);
        bv[ni] = *(const short8*)((const char*)Bs + row * 128 + (kb ^ ((row & 7) << 4)));
      }
#pragma unroll
      for (int mi = 0; mi < 4; ++mi)
#pragma unroll
        for (int ni = 0; ni < 4; ++ni)
          acc[mi][ni] = __builtin_amdgcn_mfma_f32_16x16x32_bf16(av[mi], bv[ni], acc[mi][ni], 0, 0, 0);
    }
  }

  const int lr = lane >> 4, lc = lane & 15;
#pragma unroll
  for (int ni = 0; ni < 4; ++ni) {
    int c = n0 + wn * 64 + ni * 16 + lc;
    float bb;
    if (EPI == 0) bb = bias[c] + bias[N + c] + bias[2 * N + c];
    else          bb = bias[c];
#pragma unroll
    for (int mi = 0; mi < 4; ++mi) {
      int r0 = m0 + wm * 64 + mi * 16 + lr * 4;
      f32x4 v = acc[mi][ni];
#pragma unroll
      for (int j = 0; j < 4; ++j) {
        float val = v[j] + bb;
        size_t idx = (size_t)(r0 + j) * N + c;
        if (EPI == 0) { val = val > 0.f ? val : 0.f; Cb[idx] = f2bf(val); }
        else if (EPI == 1) { Cb[idx] = f2bf(tanhf(val)); }
        else { Cf[idx] = val; }
      }
    }
  }
}

// ---------------------------------------------------------------------------
// Final GEMM, 2-blocks/CU with CORRECT geometry (round-10 fix):
// BM=BN=128, BK=64 (full 128B rows — cacheline-exact staging, proven round-8
// swizzle), 4 waves (2x2), per-wave 64x64 via 32x32x16 MFMA, double-buffered
// 64 KiB LDS -> 2 blocks/CU (LDS-capped). Counted vmcnt(8) trailer identical
// to round 8. Cross-block TLP hides the per-block vmcnt/barrier drain.
// ---------------------------------------------------------------------------
__global__ __launch_bounds__(256, 2)
void gemm8_out(const unsigned short* __restrict__ A,
               const unsigned short* __restrict__ Bt,
               const float* __restrict__ bias,
               float* __restrict__ Cf,
               int K, int N) {
  __shared__ __align__(16) unsigned short As8[2][128 * 64];  // 16 KiB each
  __shared__ __align__(16) unsigned short Bs8[2][128 * 64];  // 16 KiB each

  const int tid = threadIdx.x;
  const int lane = tid & 63;
  const int wid = tid >> 6;                       // 0..3
  const int wm = wid >> 1, wn = wid & 1;          // 2 x 2 waves

  const int bid = blockIdx.x;
  const int cpx = gridDim.x >> 3;                 // 8000/8 = 1000
  const int lid = (bid & 7) * cpx + (bid >> 3);   // T1 XCD swizzle
  const int mt = lid & 31;                        // 32 m-tiles (M = 4096)
  const int ntile = lid >> 5;                     // 250 n-tiles
  const int m0 = mt * 128, n0 = ntile * 128;
  const size_t strideB = (size_t)K * 2;
  const int kTiles = K >> 6;                      // 32

  // staging: 16 A-chunks + 16 B-chunks of 1KB (8 rows x 128B each);
  // wave w stages A chunks [4w,4w+4) and B chunks [4w,4w+4) -> 8 loads/wave.
  const int srow = lane >> 3;                          // row within chunk
  const int ssw = ((lane & 7) ^ srow) << 4;            // pre-swizzled 16B slot

  auto stage = [&](int buf, int t) {
#pragma unroll
    for (int i = 0; i < 4; ++i) {
      const int chunk = wid * 4 + i;                   // 0..15
      const int row = chunk * 8 + srow;                // 0..127
      gload_lds16((const char*)A + (size_t)(m0 + row) * strideB +
                      (size_t)t * 128 + ssw,
                  (char*)As8 + buf * 16384 + chunk * 1024);
      gload_lds16((const char*)Bt + (size_t)(n0 + row) * strideB +
                      (size_t)t * 128 + ssw,
                  (char*)Bs8 + buf * 16384 + chunk * 1024);
    }
  };

  const int l31 = lane & 31;
  const int hk16 = (lane >> 5) * 16;   // k-half byte offset within 16-k step

  f32x16 acc[2][2] = {};

  stage(0, 0);
  stage(1, 1);
  asm volatile("s_waitcnt vmcnt(8)" ::: "memory");   // tile 0 landed
  __builtin_amdgcn_sched_barrier(0);
  __builtin_amdgcn_s_barrier();

  for (int t = 0; t < kTiles; ++t) {
    const char* ab = (const char*)As8 + (t & 1) * 16384;
    const char* bb = (const char*)Bs8 + (t & 1) * 16384;
    short8 av[2][4], bv[2][4];

#pragma unroll
    for (int mi = 0; mi < 2; ++mi) {
      int r = wm * 64 + mi * 32 + l31;
      int sz = (r & 7) << 4;
#pragma unroll
      for (int ks = 0; ks < 4; ++ks)
        av[mi][ks] = *(const short8*)(ab + r * 128 + ((ks * 32 + hk16) ^ sz));
    }
#pragma unroll
    for (int ni = 0; ni < 2; ++ni) {
      int r = wn * 64 + ni * 32 + l31;
      int sz = (r & 7) << 4;
#pragma unroll
      for (int ks = 0; ks < 4; ++ks)
        bv[ni][ks] = *(const short8*)(bb + r * 128 + ((ks * 32 + hk16) ^ sz));
    }
    __builtin_amdgcn_s_setprio(1);
#pragma unroll
    for (int ks = 0; ks < 4; ++ks)
#pragma unroll
      for (int mi = 0; mi < 2; ++mi)
#pragma unroll
        for (int ni = 0; ni < 2; ++ni)
          acc[mi][ni] = __builtin_amdgcn_mfma_f32_32x32x16_bf16(
              av[mi][ks], bv[ni][ks], acc[mi][ni], 0, 0, 0);
    __builtin_amdgcn_s_setprio(0);

    // ---- trailer: counted-vmcnt double-buffer rotation (round-8 pattern) ----
    if (t + 1 < kTiles) {
      __builtin_amdgcn_sched_barrier(0);
      __builtin_amdgcn_s_barrier();          // all waves done reading buf[t&1]
      if (t + 2 < kTiles) {
        stage(t & 1, t + 2);                 // overwrite just-read buffer
        asm volatile("s_waitcnt vmcnt(8)" ::: "memory");  // tile t+1 landed
      } else {
        asm volatile("s_waitcnt vmcnt(0)" ::: "memory");
      }
      __builtin_amdgcn_sched_barrier(0);
      __builtin_amdgcn_s_barrier();          // tile t+1 visible to all waves
    }
  }

  // ---- epilogue: 32x32 C/D mapping, NT stores ----
  const int rbase = m0 + wm * 64 + 4 * (lane >> 5);
#pragma unroll
  for (int ni = 0; ni < 2; ++ni) {
    int c = n0 + wn * 64 + ni * 32 + l31;
    float bb2 = bias[c];
#pragma unroll
    for (int mi = 0; mi < 2; ++mi) {
#pragma unroll
      for (int rg = 0; rg < 16; ++rg) {
        int r = rbase + mi * 32 + (rg & 3) + 8 * (rg >> 2);
        __builtin_nontemporal_store(acc[mi][ni][rg] + bb2,
                                    &Cf[(size_t)r * N + c]);
      }
    }
  }
}

// ---------------------------------------------------------------------------
// Fallback GEMM (round-2 proven): B is f32 [K][N], converted during staging.
// ---------------------------------------------------------------------------
template <int EPI>
__global__ __launch_bounds__(256)
void gemm_bf16(const unsigned short* __restrict__ A,
               const float* __restrict__ B,
               const float* __restrict__ bias,
               unsigned short* __restrict__ Cb,
               float* __restrict__ Cf,
               int K, int N) {
  __shared__ __align__(16) unsigned short As[128 * 64];
  __shared__ __align__(16) unsigned short Bs[128 * 64];

  const int tid = threadIdx.x;
  const int lane = tid & 63;
  const int wv = tid >> 6;
  const int wm = wv >> 1, wn = wv & 1;
  const int mt = blockIdx.x & 31;
  const int nt = blockIdx.x >> 5;
  const int m0 = mt * 128, n0 = nt * 128;

  f32x4 acc[4][4] = {};

  for (int kt = 0; kt < K; kt += 64) {
    __syncthreads();
#pragma unroll
    for (int i = 0; i < 4; ++i) {
      int q = tid + 256 * i;
      int row = q >> 3;
      int kc = q & 7;
      uint4v v = *(const uint4v*)((const char*)A +
                   ((size_t)(m0 + row) * K + kt) * 2 + kc * 16);
      *(uint4v*)((char*)As + row * 128 + ((kc * 16) ^ ((row & 7) << 4))) = v;
    }
#pragma unroll
    for (int gi = 0; gi < 4; ++gi) {
      int q = tid + 256 * gi;
      int nn = q & 127;
      int k8 = q >> 7;
      const float* src = B + (size_t)(kt + k8 * 8) * N + (n0 + nn);
      ushort8 tv;
#pragma unroll
      for (int j = 0; j < 8; ++j) tv[j] = f2bf(src[(size_t)j * N]);
      *(ushort8*)((char*)Bs + nn * 128 + ((k8 * 16) ^ ((nn & 7) << 4))) = tv;
    }
    __syncthreads();
#pragma unroll
    for (int kk = 0; kk < 2; ++kk) {
      short8 av[4], bv[4];
      const int kb = kk * 64 + (lane >> 4) * 16;
#pragma unroll
      for (int mi = 0; mi < 4; ++mi) {
        int row = wm * 64 + mi * 16 + (lane & 15);
        av[mi] = *(const short8*)((const char*)As + row * 128 + (kb ^ ((row & 7) << 4)));
      }
#pragma unroll
      for (int ni = 0; ni < 4; ++ni) {
        int row = wn * 64 + ni * 16 + (lane & 15);
        bv[ni] = *(const short8*)((const char*)Bs + row * 128 + (kb ^ ((row & 7) << 4)));
      }
#pragma unroll
      for (int mi = 0; mi < 4; ++mi)
#pragma unroll
        for (int ni = 0; ni < 4; ++ni)
          acc[mi][ni] = __builtin_amdgcn_mfma_f32_16x16x32_bf16(av[mi], bv[ni], acc[mi][ni], 0, 0, 0);
    }
  }

  const int lr = lane >> 4, lc = lane & 15;
#pragma unroll
  for (int ni = 0; ni < 4; ++ni) {
    int c = n0 + wn * 64 + ni * 16 + lc;
    float bb = bias[c];
#pragma unroll
    for (int mi = 0; mi < 4; ++mi) {
      int r0 = m0 + wm * 64 + mi * 16 + lr * 4;
      f32x4 v = acc[mi][ni];
#pragma unroll
      for (int j = 0; j < 4; ++j) {
        float val = v[j] + bb;
        size_t idx = (size_t)(r0 + j) * N + c;
        if (EPI == 1) { Cb[idx] = f2bf(tanhf(val)); }
        else { Cf[idx] = val; }
      }
    }
  }
}

// ---------------------------------------------------------------------------
extern "C" void kernel_launch(void* const* d_in, const int* in_sizes, int n_in,
                              void* d_out, int out_size, void* d_ws, size_t ws_size,
                              hipStream_t stream) {
  const float* x     = (const float*)d_in[0];  // [4,1024,3072]
  const float* w     = (const float*)d_in[1];  // [3,3072]
  const float* emb_w = (const float*)d_in[2];  // [3072,2048]
  const float* emb_b = (const float*)d_in[3];  // [3,2048]
  const float* lin_w = (const float*)d_in[4];  // [2,2048,2048]
  const float* lin_b = (const float*)d_in[5];  // [2,2048]
  const float* out_w = (const float*)d_in[6];  // [2048,32000]
  const float* out_b = (const float*)d_in[7];  // [32000]
  float* out = (float*)d_out;                  // [4096,32000] f32

  char* ob = (char*)d_out;
  unsigned short* xg      = (unsigned short*)ob;
  unsigned short* h0      = (unsigned short*)(ob + (((size_t)128) << 20));
  unsigned short* h1      = (unsigned short*)(ob + (((size_t)160) << 20));
  unsigned short* emb_wT  = (unsigned short*)(ob + (((size_t)192) << 20));
  unsigned short* lin_wT0 = (unsigned short*)(ob + (((size_t)208) << 20));
  unsigned short* lin_wT1 = (unsigned short*)(ob + (((size_t)224) << 20));
  unsigned short* h2      = (unsigned short*)d_ws;
  unsigned short* out_wT  = (unsigned short*)((char*)d_ws + (((size_t)32) << 20));
  const bool fast4 = ws_size >= ((((size_t)32) << 20) + (size_t)32000 * 2048 * 2);

  // gates + small weight transposes (independent), one launch
  gates_or_tc<<<4096 + 3584, 256, 0, stream>>>(x, w, xg, emb_w, emb_wT,
                                               lin_w, lin_wT0, lin_wT1);
  // mid GEMM 0 overlapped with out_w transpose
  if (fast4)
    gemm0_or_tc<<<512 + 16000, 256, 0, stream>>>(xg, emb_wT, emb_b, h0,
                                                 out_w, out_wT, 1);
  else
    gemm0_or_tc<<<512, 256, 0, stream>>>(xg, emb_wT, emb_b, h0,
                                         out_w, out_wT, 0);

  gemm_tt<1><<<32 * 16, 256, 0, stream>>>(h0, lin_wT0, lin_b, h1, nullptr, 2048, 2048);
  gemm_tt<1><<<32 * 16, 256, 0, stream>>>(h1, lin_wT1, lin_b + 2048, h2, nullptr, 2048, 2048);
  if (fast4)
    gemm8_out<<<32 * 250, 256, 0, stream>>>(h2, out_wT, out_b, out, 2048, 32000);
  else
    gemm_bf16<2><<<32 * 250, 256, 0, stream>>>(h2, out_w, out_b, nullptr, out, 2048, 32000);
}

// Round 12
// 885.229 us; speedup vs baseline: 1.1972x; 1.1972x over previous
//
#include <hip/hip_runtime.h>
#include <math.h>

typedef __attribute__((ext_vector_type(8))) short short8;
typedef __attribute__((ext_vector_type(8))) unsigned short ushort8;
typedef __attribute__((ext_vector_type(4))) unsigned short ushort4v;
typedef __attribute__((ext_vector_type(4))) unsigned int uint4v;
typedef __attribute__((ext_vector_type(4))) float f32x4;
typedef __attribute__((ext_vector_type(16))) float f32x16;

__device__ __forceinline__ unsigned short f2bf(float f) {
  union { float f; unsigned u; } v; v.f = f;
  unsigned u = v.u;
  return (unsigned short)((u + 0x7fffu + ((u >> 16) & 1u)) >> 16);
}

__device__ __forceinline__ void gload_lds16(const void* g, void* lds) {
  __builtin_amdgcn_global_load_lds(
      (const __attribute__((address_space(1))) unsigned int*)g,
      (__attribute__((address_space(3))) unsigned int*)lds, 16, 0, 0);
}

// ---------------------------------------------------------------------------
// Transpose+convert body: in f32 [R][C] row-major -> out bf16 [C][R] row-major,
// one 64x64 tile at (r0, c0), using caller-provided LDS (>= 64*65*4 bytes).
// ---------------------------------------------------------------------------
__device__ __forceinline__ void tc_body(const float* __restrict__ in,
                                        unsigned short* __restrict__ outp,
                                        int R, int C, int r0, int c0,
                                        char* smem) {
  float (*tile)[65] = (float(*)[65])smem;
  const int t = threadIdx.x;
  const int tr = t >> 4;
  const int tc = (t & 15) * 4;
#pragma unroll
  for (int p = 0; p < 4; ++p) {
    int r = p * 16 + tr;
    f32x4 v = *(const f32x4*)(in + (size_t)(r0 + r) * C + c0 + tc);
    tile[r][tc] = v[0]; tile[r][tc + 1] = v[1];
    tile[r][tc + 2] = v[2]; tile[r][tc + 3] = v[3];
  }
  __syncthreads();
  const int c = t >> 2;
  const int rb = (t & 3) * 16;
  ushort8 o0, o1;
#pragma unroll
  for (int j = 0; j < 8; ++j) o0[j] = f2bf(tile[rb + j][c]);
#pragma unroll
  for (int j = 0; j < 8; ++j) o1[j] = f2bf(tile[rb + 8 + j][c]);
  unsigned short* dst = outp + (size_t)(c0 + c) * R + r0 + rb;
  *(ushort8*)dst = o0;
  *(ushort8*)(dst + 8) = o1;
}

// ---------------------------------------------------------------------------
// Fused kernel A: blocks [0,4096) = gates; [4096,7680) = small transposes
// (emb_wT 1536, lin_wT0 1024, lin_wT1 1024). All independent.
// ---------------------------------------------------------------------------
__global__ __launch_bounds__(256)
void gates_or_tc(const float* __restrict__ x, const float* __restrict__ w,
                 unsigned short* __restrict__ xg,
                 const float* __restrict__ emb_w, unsigned short* __restrict__ emb_wT,
                 const float* __restrict__ lin_w,
                 unsigned short* __restrict__ lin_wT0,
                 unsigned short* __restrict__ lin_wT1) {
  __shared__ __align__(16) char smem[64 * 65 * 4];
  __shared__ float sred[4][3];
  const int bid = blockIdx.x;
  const int t = threadIdx.x;

  if (bid >= 4096) {
    int b2 = bid - 4096;
    if (b2 < 1536) {
      tc_body(emb_w, emb_wT, 3072, 2048, (b2 >> 5) * 64, (b2 & 31) * 64, smem);
    } else {
      int b3 = b2 - 1536;
      const float* in = (b3 < 1024) ? lin_w : (lin_w + 2048 * 2048);
      unsigned short* outp = (b3 < 1024) ? lin_wT0 : lin_wT1;
      b3 &= 1023;
      tc_body(in, outp, 2048, 2048, (b3 >> 5) * 64, (b3 & 31) * 64, smem);
    }
    return;
  }

  const int n = bid;
  const float* xr = x + (size_t)n * 3072;
  f32x4 xv[3];
#pragma unroll
  for (int c = 0; c < 3; ++c)
    xv[c] = *(const f32x4*)(xr + c * 1024 + t * 4);

  float p[3] = {0.f, 0.f, 0.f};
#pragma unroll
  for (int l = 0; l < 3; ++l) {
#pragma unroll
    for (int c = 0; c < 3; ++c) {
      f32x4 wv = *(const f32x4*)(w + l * 3072 + c * 1024 + t * 4);
      p[l] += xv[c][0] * wv[0] + xv[c][1] * wv[1] + xv[c][2] * wv[2] + xv[c][3] * wv[3];
    }
  }
#pragma unroll
  for (int off = 32; off; off >>= 1) {
    p[0] += __shfl_xor(p[0], off);
    p[1] += __shfl_xor(p[1], off);
    p[2] += __shfl_xor(p[2], off);
  }
  const int wave = t >> 6, lane = t & 63;
  if (lane == 0) {
    sred[wave][0] = p[0]; sred[wave][1] = p[1]; sred[wave][2] = p[2];
  }
  __syncthreads();
  float g[3];
#pragma unroll
  for (int l = 0; l < 3; ++l) {
    float s = sred[0][l] + sred[1][l] + sred[2][l] + sred[3][l];
    g[l] = 1.f / (1.f + expf(-s));
  }
  unsigned short* orow = xg + (size_t)n * 3072;
#pragma unroll
  for (int c = 0; c < 3; ++c) {
    ushort4v o;
#pragma unroll
    for (int j = 0; j < 4; ++j) o[j] = f2bf(xv[c][j] * g[c]);
    *(ushort4v*)(orow + c * 1024 + t * 4) = o;
  }
}

// ---------------------------------------------------------------------------
// Fused kernel B: blocks [0,512) = mid GEMM 0 (h0 = relu(xg @ emb_wT^T + b)),
// blocks [512, 512+16000) = out_w transpose (2048 x 32000 -> 32000 x 2048).
// ---------------------------------------------------------------------------
__global__ __launch_bounds__(256)
void gemm0_or_tc(const unsigned short* __restrict__ A,
                 const unsigned short* __restrict__ Bt,
                 const float* __restrict__ bias,
                 unsigned short* __restrict__ Cb,
                 const float* __restrict__ tc_in,
                 unsigned short* __restrict__ tc_out,
                 int do_tc) {
  __shared__ __align__(16) char smem[32768];
  const int bid = blockIdx.x;

  if (bid >= 512) {
    int b2 = bid - 512;
    tc_body(tc_in, tc_out, 2048, 32000, (b2 / 500) * 64, (b2 % 500) * 64, smem);
    return;
  }
  (void)do_tc;

  unsigned short* As = (unsigned short*)smem;
  unsigned short* Bs = (unsigned short*)(smem + 16384);
  constexpr int K = 3072, N = 2048;

  const int tid = threadIdx.x;
  const int lane = tid & 63;
  const int wv = tid >> 6;
  const int wm = wv >> 1, wn = wv & 1;
  const int lid = (bid & 7) * 64 + (bid >> 3);   // XCD swizzle over 512 blocks
  const int mt = lid & 31;
  const int nt = lid >> 5;
  const int m0 = mt * 128, n0 = nt * 128;
  const size_t strideB = (size_t)K * 2;

  f32x4 acc[4][4] = {};

  for (int kt = 0; kt < K; kt += 64) {
    __syncthreads();
#pragma unroll
    for (int i = 0; i < 4; ++i) {
      const int o = wv * 4096 + i * 1024 + lane * 16;
      const int row = o >> 7;
      const int sw = (((o >> 4) & 7) * 16) ^ ((row & 7) << 4);
      gload_lds16((const char*)A + (size_t)(m0 + row) * strideB + (size_t)kt * 2 + sw,
                  (char*)As + wv * 4096 + i * 1024);
      gload_lds16((const char*)Bt + (size_t)(n0 + row) * strideB + (size_t)kt * 2 + sw,
                  (char*)Bs + wv * 4096 + i * 1024);
    }
    __syncthreads();
#pragma unroll
    for (int kk = 0; kk < 2; ++kk) {
      short8 av[4], bv[4];
      const int kb = kk * 64 + (lane >> 4) * 16;
#pragma unroll
      for (int mi = 0; mi < 4; ++mi) {
        int row = wm * 64 + mi * 16 + (lane & 15);
        av[mi] = *(const short8*)((const char*)As + row * 128 + (kb ^ ((row & 7) << 4)));
      }
#pragma unroll
      for (int ni = 0; ni < 4; ++ni) {
        int row = wn * 64 + ni * 16 + (lane & 15);
        bv[ni] = *(const short8*)((const char*)Bs + row * 128 + (kb ^ ((row & 7) << 4)));
      }
#pragma unroll
      for (int mi = 0; mi < 4; ++mi)
#pragma unroll
        for (int ni = 0; ni < 4; ++ni)
          acc[mi][ni] = __builtin_amdgcn_mfma_f32_16x16x32_bf16(av[mi], bv[ni], acc[mi][ni], 0, 0, 0);
    }
  }

  const int lr = lane >> 4, lc = lane & 15;
#pragma unroll
  for (int ni = 0; ni < 4; ++ni) {
    int c = n0 + wn * 64 + ni * 16 + lc;
    float bb = bias[c] + bias[N + c] + bias[2 * N + c];
#pragma unroll
    for (int mi = 0; mi < 4; ++mi) {
      int r0 = m0 + wm * 64 + mi * 16 + lr * 4;
      f32x4 v = acc[mi][ni];
#pragma unroll
      for (int j = 0; j < 4; ++j) {
        float val = v[j] + bb;
        val = val > 0.f ? val : 0.f;
        Cb[(size_t)(r0 + j) * N + c] = f2bf(val);
      }
    }
  }
}

// ---------------------------------------------------------------------------
// Mid GEMM (proven, m97-structure): C[4096, N] = A(bf16) @ Bt(bf16)^T
// + XCD-aware block swizzle (grid % 8 == 0).
// ---------------------------------------------------------------------------
template <int EPI>
__global__ __launch_bounds__(256)
void gemm_tt(const unsigned short* __restrict__ A,
             const unsigned short* __restrict__ Bt,
             const float* __restrict__ bias,
             unsigned short* __restrict__ Cb,
             float* __restrict__ Cf,
             int K, int N) {
  __shared__ __align__(16) unsigned short As[128 * 64];
  __shared__ __align__(16) unsigned short Bs[128 * 64];

  const int tid = threadIdx.x;
  const int lane = tid & 63;
  const int wv = tid >> 6;
  const int wm = wv >> 1, wn = wv & 1;
  const int bid = blockIdx.x;
  const int cpx = gridDim.x >> 3;
  const int lid = (bid & 7) * cpx + (bid >> 3);   // XCD swizzle (grid%8==0)
  const int mt = lid & 31;
  const int nt = lid >> 5;
  const int m0 = mt * 128, n0 = nt * 128;
  const size_t strideB = (size_t)K * 2;

  f32x4 acc[4][4] = {};

  for (int kt = 0; kt < K; kt += 64) {
    __syncthreads();
#pragma unroll
    for (int i = 0; i < 4; ++i) {
      const int o = wv * 4096 + i * 1024 + lane * 16;
      const int row = o >> 7;
      const int sw = (((o >> 4) & 7) * 16) ^ ((row & 7) << 4);
      gload_lds16((const char*)A + (size_t)(m0 + row) * strideB + (size_t)kt * 2 + sw,
                  (char*)As + wv * 4096 + i * 1024);
      gload_lds16((const char*)Bt + (size_t)(n0 + row) * strideB + (size_t)kt * 2 + sw,
                  (char*)Bs + wv * 4096 + i * 1024);
    }
    __syncthreads();
#pragma unroll
    for (int kk = 0; kk < 2; ++kk) {
      short8 av[4], bv[4];
      const int kb = kk * 64 + (lane >> 4) * 16;
#pragma unroll
      for (int mi = 0; mi < 4; ++mi) {
        int row = wm * 64 + mi * 16 + (lane & 15);
        av[mi] = *(const short8*)((const char*)As + row * 128 + (kb ^ ((row & 7) << 4)));
      }
#pragma unroll
      for (int ni = 0; ni < 4; ++ni) {
        int row = wn * 64 + ni * 16 + (lane & 15);
        bv[ni] = *(const short8*)((const char*)Bs + row * 128 + (kb ^ ((row & 7) << 4)));
      }
#pragma unroll
      for (int mi = 0; mi < 4; ++mi)
#pragma unroll
        for (int ni = 0; ni < 4; ++ni)
          acc[mi][ni] = __builtin_amdgcn_mfma_f32_16x16x32_bf16(av[mi], bv[ni], acc[mi][ni], 0, 0, 0);
    }
  }

  const int lr = lane >> 4, lc = lane & 15;
#pragma unroll
  for (int ni = 0; ni < 4; ++ni) {
    int c = n0 + wn * 64 + ni * 16 + lc;
    float bb;
    if (EPI == 0) bb = bias[c] + bias[N + c] + bias[2 * N + c];
    else          bb = bias[c];
#pragma unroll
    for (int mi = 0; mi < 4; ++mi) {
      int r0 = m0 + wm * 64 + mi * 16 + lr * 4;
      f32x4 v = acc[mi][ni];
#pragma unroll
      for (int j = 0; j < 4; ++j) {
        float val = v[j] + bb;
        size_t idx = (size_t)(r0 + j) * N + c;
        if (EPI == 0) { val = val > 0.f ? val : 0.f; Cb[idx] = f2bf(val); }
        else if (EPI == 1) { Cb[idx] = f2bf(tanhf(val)); }
        else { Cf[idx] = val; }
      }
    }
  }
}

// ---------------------------------------------------------------------------
// Final GEMM (round-8 proven): 256x256x64, 8 waves, dbuf LDS, counted vmcnt
// trailer, setprio, XCD swizzle, NT stores, 32x32x16 MFMA.
// ---------------------------------------------------------------------------
__global__ __launch_bounds__(512, 2)
void gemm8_out(const unsigned short* __restrict__ A,
               const unsigned short* __restrict__ Bt,
               const float* __restrict__ bias,
               float* __restrict__ Cf,
               int K, int N) {
  __shared__ __align__(16) unsigned short As8[2][256 * 64];  // 64 KiB
  __shared__ __align__(16) unsigned short Bs8[2][256 * 64];  // 64 KiB

  const int tid = threadIdx.x;
  const int lane = tid & 63;
  const int wid = tid >> 6;
  const int wm = wid >> 2, wn = wid & 3;

  const int bid = blockIdx.x;
  const int cpx = gridDim.x >> 3;                 // grid % 8 == 0
  const int lid = (bid & 7) * cpx + (bid >> 3);   // T1 XCD swizzle
  const int mt = lid & 15;                        // 16 m-tiles (M = 4096)
  const int ntile = lid >> 4;
  const int m0 = mt * 256, n0 = ntile * 256;
  const size_t strideB = (size_t)K * 2;
  const int kTiles = K >> 6;

  const unsigned short* smat = (wid < 4) ? A : Bt;
  char* sb = (wid < 4) ? (char*)As8 : (char*)Bs8;
  const int part = wid & 3;
  const int srow0 = ((wid < 4) ? m0 : n0) + part * 64 + (lane >> 3);
  const int ssw = ((lane & 7) ^ (lane >> 3)) << 4;

  auto stage8 = [&](int buf, int t) {
#pragma unroll
    for (int i = 0; i < 8; ++i)
      gload_lds16((const char*)smat + (size_t)(srow0 + i * 8) * strideB +
                      (size_t)t * 128 + ssw,
                  sb + buf * 32768 + part * 8192 + i * 1024);
  };

  const int l31 = lane & 31;
  const int hk16 = (lane >> 5) * 16;

  f32x16 acc[4][2] = {};

  stage8(0, 0);
  stage8(1, 1);
  asm volatile("s_waitcnt vmcnt(8)" ::: "memory");
  __builtin_amdgcn_sched_barrier(0);
  __builtin_amdgcn_s_barrier();

  for (int t = 0; t < kTiles; ++t) {
    const char* ab = (const char*)As8 + (t & 1) * 32768;
    const char* bb = (const char*)Bs8 + (t & 1) * 32768;
    short8 av[2][4], bva[4], bvb[4];

    // ---- phase 1 ----
#pragma unroll
    for (int mi = 0; mi < 2; ++mi) {
      int r = wm * 128 + mi * 32 + l31;
      int sz = (r & 7) << 4;
#pragma unroll
      for (int ks = 0; ks < 4; ++ks)
        av[mi][ks] = *(const short8*)(ab + r * 128 + ((ks * 32 + hk16) ^ sz));
    }
    {
      int r = wn * 64 + l31;
      int sz = (r & 7) << 4;
#pragma unroll
      for (int ks = 0; ks < 4; ++ks)
        bva[ks] = *(const short8*)(bb + r * 128 + ((ks * 32 + hk16) ^ sz));
    }
    __builtin_amdgcn_s_setprio(1);
#pragma unroll
    for (int ks = 0; ks < 4; ++ks)
#pragma unroll
      for (int mi = 0; mi < 2; ++mi)
        acc[mi][0] = __builtin_amdgcn_mfma_f32_32x32x16_bf16(
            av[mi][ks], bva[ks], acc[mi][0], 0, 0, 0);
    __builtin_amdgcn_s_setprio(0);

    // ---- phase 2 ----
    {
      int r = wn * 64 + 32 + l31;
      int sz = (r & 7) << 4;
#pragma unroll
      for (int ks = 0; ks < 4; ++ks)
        bvb[ks] = *(const short8*)(bb + r * 128 + ((ks * 32 + hk16) ^ sz));
    }
    __builtin_amdgcn_s_setprio(1);
#pragma unroll
    for (int ks = 0; ks < 4; ++ks)
#pragma unroll
      for (int mi = 0; mi < 2; ++mi)
        acc[mi][1] = __builtin_amdgcn_mfma_f32_32x32x16_bf16(
            av[mi][ks], bvb[ks], acc[mi][1], 0, 0, 0);
    __builtin_amdgcn_s_setprio(0);

    // ---- phase 3 ----
#pragma unroll
    for (int mi = 0; mi < 2; ++mi) {
      int r = wm * 128 + 64 + mi * 32 + l31;
      int sz = (r & 7) << 4;
#pragma unroll
      for (int ks = 0; ks < 4; ++ks)
        av[mi][ks] = *(const short8*)(ab + r * 128 + ((ks * 32 + hk16) ^ sz));
    }
    __builtin_amdgcn_s_setprio(1);
#pragma unroll
    for (int ks = 0; ks < 4; ++ks)
#pragma unroll
      for (int mi = 0; mi < 2; ++mi)
        acc[2 + mi][1] = __builtin_amdgcn_mfma_f32_32x32x16_bf16(
            av[mi][ks], bvb[ks], acc[2 + mi][1], 0, 0, 0);
    __builtin_amdgcn_s_setprio(0);

    // ---- phase 4 ----
    __builtin_amdgcn_s_setprio(1);
#pragma unroll
    for (int ks = 0; ks < 4; ++ks)
#pragma unroll
      for (int mi = 0; mi < 2; ++mi)
        acc[2 + mi][0] = __builtin_amdgcn_mfma_f32_32x32x16_bf16(
            av[mi][ks], bva[ks], acc[2 + mi][0], 0, 0, 0);
    __builtin_amdgcn_s_setprio(0);

    // ---- trailer ----
    if (t + 1 < kTiles) {
      __builtin_amdgcn_sched_barrier(0);
      __builtin_amdgcn_s_barrier();
      if (t + 2 < kTiles) {
        stage8(t & 1, t + 2);
        asm volatile("s_waitcnt vmcnt(8)" ::: "memory");
      } else {
        asm volatile("s_waitcnt vmcnt(0)" ::: "memory");
      }
      __builtin_amdgcn_sched_barrier(0);
      __builtin_amdgcn_s_barrier();
    }
  }

  // ---- epilogue: 32x32 C/D mapping, NT stores ----
  const int rbase = m0 + wm * 128 + 4 * (lane >> 5);
#pragma unroll
  for (int ni = 0; ni < 2; ++ni) {
    int c = n0 + wn * 64 + ni * 32 + l31;
    float bb2 = bias[c];
#pragma unroll
    for (int mi = 0; mi < 4; ++mi) {
#pragma unroll
      for (int rg = 0; rg < 16; ++rg) {
        int r = rbase + mi * 32 + (rg & 3) + 8 * (rg >> 2);
        __builtin_nontemporal_store(acc[mi][ni][rg] + bb2,
                                    &Cf[(size_t)r * N + c]);
      }
    }
  }
}

// ---------------------------------------------------------------------------
// Fallback GEMM (round-2 proven): B is f32 [K][N], converted during staging.
// ---------------------------------------------------------------------------
template <int EPI>
__global__ __launch_bounds__(256)
void gemm_bf16(const unsigned short* __restrict__ A,
               const float* __restrict__ B,
               const float* __restrict__ bias,
               unsigned short* __restrict__ Cb,
               float* __restrict__ Cf,
               int K, int N) {
  __shared__ __align__(16) unsigned short As[128 * 64];
  __shared__ __align__(16) unsigned short Bs[128 * 64];

  const int tid = threadIdx.x;
  const int lane = tid & 63;
  const int wv = tid >> 6;
  const int wm = wv >> 1, wn = wv & 1;
  const int mt = blockIdx.x & 31;
  const int nt = blockIdx.x >> 5;
  const int m0 = mt * 128, n0 = nt * 128;

  f32x4 acc[4][4] = {};

  for (int kt = 0; kt < K; kt += 64) {
    __syncthreads();
#pragma unroll
    for (int i = 0; i < 4; ++i) {
      int q = tid + 256 * i;
      int row = q >> 3;
      int kc = q & 7;
      uint4v v = *(const uint4v*)((const char*)A +
                   ((size_t)(m0 + row) * K + kt) * 2 + kc * 16);
      *(uint4v*)((char*)As + row * 128 + ((kc * 16) ^ ((row & 7) << 4))) = v;
    }
#pragma unroll
    for (int gi = 0; gi < 4; ++gi) {
      int q = tid + 256 * gi;
      int nn = q & 127;
      int k8 = q >> 7;
      const float* src = B + (size_t)(kt + k8 * 8) * N + (n0 + nn);
      ushort8 tv;
#pragma unroll
      for (int j = 0; j < 8; ++j) tv[j] = f2bf(src[(size_t)j * N]);
      *(ushort8*)((char*)Bs + nn * 128 + ((k8 * 16) ^ ((nn & 7) << 4))) = tv;
    }
    __syncthreads();
#pragma unroll
    for (int kk = 0; kk < 2; ++kk) {
      short8 av[4], bv[4];
      const int kb = kk * 64 + (lane >> 4) * 16;
#pragma unroll
      for (int mi = 0; mi < 4; ++mi) {
        int row = wm * 64 + mi * 16 + (lane & 15);
        av[mi] = *(const short8*)((const char*)As + row * 128 + (kb ^ ((row & 7) << 4)));
      }
#pragma unroll
      for (int ni = 0; ni < 4; ++ni) {
        int row = wn * 64 + ni * 16 + (lane & 15);
        bv[ni] = *(const short8*)((const char*)Bs + row * 128 + (kb ^ ((row & 7) << 4)));
      }
#pragma unroll
      for (int mi = 0; mi < 4; ++mi)
#pragma unroll
        for (int ni = 0; ni < 4; ++ni)
          acc[mi][ni] = __builtin_amdgcn_mfma_f32_16x16x32_bf16(av[mi], bv[ni], acc[mi][ni], 0, 0, 0);
    }
  }

  const int lr = lane >> 4, lc = lane & 15;
#pragma unroll
  for (int ni = 0; ni < 4; ++ni) {
    int c = n0 + wn * 64 + ni * 16 + lc;
    float bb = bias[c];
#pragma unroll
    for (int mi = 0; mi < 4; ++mi) {
      int r0 = m0 + wm * 64 + mi * 16 + lr * 4;
      f32x4 v = acc[mi][ni];
#pragma unroll
      for (int j = 0; j < 4; ++j) {
        float val = v[j] + bb;
        size_t idx = (size_t)(r0 + j) * N + c;
        if (EPI == 1) { Cb[idx] = f2bf(tanhf(val)); }
        else { Cf[idx] = val; }
      }
    }
  }
}

// ---------------------------------------------------------------------------
extern "C" void kernel_launch(void* const* d_in, const int* in_sizes, int n_in,
                              void* d_out, int out_size, void* d_ws, size_t ws_size,
                              hipStream_t stream) {
  const float* x     = (const float*)d_in[0];  // [4,1024,3072]
  const float* w     = (const float*)d_in[1];  // [3,3072]
  const float* emb_w = (const float*)d_in[2];  // [3072,2048]
  const float* emb_b = (const float*)d_in[3];  // [3,2048]
  const float* lin_w = (const float*)d_in[4];  // [2,2048,2048]
  const float* lin_b = (const float*)d_in[5];  // [2,2048]
  const float* out_w = (const float*)d_in[6];  // [2048,32000]
  const float* out_b = (const float*)d_in[7];  // [32000]
  float* out = (float*)d_out;                  // [4096,32000] f32

  char* ob = (char*)d_out;
  unsigned short* xg      = (unsigned short*)ob;
  unsigned short* h0      = (unsigned short*)(ob + (((size_t)128) << 20));
  unsigned short* h1      = (unsigned short*)(ob + (((size_t)160) << 20));
  unsigned short* emb_wT  = (unsigned short*)(ob + (((size_t)192) << 20));
  unsigned short* lin_wT0 = (unsigned short*)(ob + (((size_t)208) << 20));
  unsigned short* lin_wT1 = (unsigned short*)(ob + (((size_t)224) << 20));
  unsigned short* h2      = (unsigned short*)d_ws;
  unsigned short* out_wT  = (unsigned short*)((char*)d_ws + (((size_t)32) << 20));
  const bool fast4 = ws_size >= ((((size_t)32) << 20) + (size_t)32000 * 2048 * 2);

  // gates + small weight transposes (independent), one launch
  gates_or_tc<<<4096 + 3584, 256, 0, stream>>>(x, w, xg, emb_w, emb_wT,
                                               lin_w, lin_wT0, lin_wT1);
  // mid GEMM 0 overlapped with out_w transpose
  if (fast4)
    gemm0_or_tc<<<512 + 16000, 256, 0, stream>>>(xg, emb_wT, emb_b, h0,
                                                 out_w, out_wT, 1);
  else
    gemm0_or_tc<<<512, 256, 0, stream>>>(xg, emb_wT, emb_b, h0,
                                         out_w, out_wT, 0);

  gemm_tt<1><<<32 * 16, 256, 0, stream>>>(h0, lin_wT0, lin_b, h1, nullptr, 2048, 2048);
  gemm_tt<1><<<32 * 16, 256, 0, stream>>>(h1, lin_wT1, lin_b + 2048, h2, nullptr, 2048, 2048);
  if (fast4)
    gemm8_out<<<16 * 125, 512, 0, stream>>>(h2, out_wT, out_b, out, 2048, 32000);
  else
    gemm_bf16<2><<<32 * 250, 256, 0, stream>>>(h2, out_w, out_b, nullptr, out, 2048, 32000);
}